// Round 1
// baseline (1333.520 us; speedup 1.0000x reference)
//
#include <hip/hip_runtime.h>
#include <cstdint>
#include <cstddef>

#define NB 16
#define NC 64
#define NFIN 192
#define HW 4096
#define SLICE ((size_t)(NB*NC*HW))   // 4194304 floats per state
#define NSTEP 16

// ws layout (float offsets)
#define WS_WT    ((size_t)0)          // wT  [16][192][64] = 196608
#define WS_BV    ((size_t)196608)     // bvec[16][64]      = 1024
#define WS_LATT  ((size_t)197632)     // latT[512][16]     = 8192
#define WS_STATS ((size_t)205824)     // stats[16][192][2] = 6144
#define WS_P1    ((size_t)211968)     // p1 [16][64][4096] = 4194304
#define WS_P2    ((size_t)4406272)    // p2 [16][64][4096] = 4194304
// total = 8600576 floats = 34.4 MB

__global__ void k_latT(const float* __restrict__ lat, float* __restrict__ latT) {
  int t = threadIdx.x;
  for (int idx = t; idx < 16*512; idx += 256) {
    int b = idx >> 9, k = idx & 511;
    latT[k*16 + b] = lat[idx];
  }
}

// wT[b][c][o] = (lat @ Wk + bk) at j = o*192 + c ; bvec[b][o] = lat @ Wb + bb
__global__ __launch_bounds__(256) void k_w(const float* __restrict__ latT,
    const float* __restrict__ Wk, const float* __restrict__ bk,
    const float* __restrict__ Wb, const float* __restrict__ bb,
    float* __restrict__ wT, float* __restrict__ bvec) {
  int t = threadIdx.x;
  if (blockIdx.x < 48) {
    int j = blockIdx.x*256 + t;
    float acc[16];
#pragma unroll
    for (int b = 0; b < 16; b++) acc[b] = 0.f;
#pragma unroll 4
    for (int k = 0; k < 512; k++) {
      float wv = Wk[(size_t)k*12288 + j];
      const float* lt = (const float*)__builtin_assume_aligned(latT + k*16, 64);
#pragma unroll
      for (int b = 0; b < 16; b++) acc[b] = fmaf(lt[b], wv, acc[b]);
    }
    int o = j / NFIN, c = j % NFIN;
    float bkj = bk[j];
#pragma unroll
    for (int b = 0; b < 16; b++) wT[(size_t)b*12288 + c*64 + o] = acc[b] + bkj;
  } else if (t < 64) {
    int j = t;
    float acc[16];
#pragma unroll
    for (int b = 0; b < 16; b++) acc[b] = 0.f;
    for (int k = 0; k < 512; k++) {
      float wv = Wb[k*64 + j];
      const float* lt = (const float*)__builtin_assume_aligned(latT + k*16, 64);
#pragma unroll
      for (int b = 0; b < 16; b++) acc[b] = fmaf(lt[b], wv, acc[b]);
    }
    float bbj = bb[j];
#pragma unroll
    for (int b = 0; b < 16; b++) bvec[b*64 + j] = acc[b] + bbj;
  }
}

// embs slice 0: zeros except [b][0][32][32] = 1
__global__ void k_init(float* __restrict__ e0) {
  int idx4 = (blockIdx.x*256 + threadIdx.x) * 4;
  float4 v = make_float4(0.f, 0.f, 0.f, 0.f);
  if ((idx4 & 262143) == 2080) v.x = 1.0f;  // 2080 = 32*64+32, channel 0
  *(float4*)(e0 + idx4) = v;
}

// Sobel conv + raw stats. block = (c, b); image channel in LDS.
__global__ __launch_bounds__(256) void k_cs(const float* __restrict__ st,
    float* __restrict__ p1, float* __restrict__ p2, float* __restrict__ stats) {
  int c = blockIdx.x, b = blockIdx.y, t = threadIdx.x;
  __shared__ float img[HW];
  __shared__ float red[4][6];
  const size_t chan = (size_t)(b*NC + c) * HW;
  const float4* src4 = (const float4*)(st + chan);
  float4* img4 = (float4*)img;
#pragma unroll
  for (int i = 0; i < 4; i++) img4[i*256 + t] = src4[i*256 + t];
  __syncthreads();
  float s0=0,q0=0,s1=0,q1=0,s2=0,q2=0;
  float* p1d = p1 + chan;
  float* p2d = p2 + chan;
#pragma unroll
  for (int i = 0; i < 4; i++) {
    int base = i*1024 + t*4;
    int h = base >> 6, w0 = base & 63;
    float gxv[4], gyv[4];
#pragma unroll
    for (int jj = 0; jj < 4; jj++) {
      int w = w0 + jj;
      bool wl = (w > 0), wr = (w < 63), hu = (h > 0), hd = (h < 63);
      float a00 = (hu && wl) ? img[(h-1)*64 + (w-1)] : 0.f;
      float a01 =  hu        ? img[(h-1)*64 +  w   ] : 0.f;
      float a02 = (hu && wr) ? img[(h-1)*64 + (w+1)] : 0.f;
      float a10 =  wl        ? img[ h   *64 + (w-1)] : 0.f;
      float a12 =  wr        ? img[ h   *64 + (w+1)] : 0.f;
      float a20 = (hd && wl) ? img[(h+1)*64 + (w-1)] : 0.f;
      float a21 =  hd        ? img[(h+1)*64 +  w   ] : 0.f;
      float a22 = (hd && wr) ? img[(h+1)*64 + (w+1)] : 0.f;
      float v = img[h*64 + w];
      float gx = (a02 - a00 + 2.f*(a12 - a10) + a22 - a20) * 0.125f;
      float gy = (a20 - a00 + 2.f*(a21 - a01) + a22 - a02) * 0.125f;
      gxv[jj] = gx; gyv[jj] = gy;
      s0 += v;  q0 = fmaf(v, v, q0);
      s1 += gx; q1 = fmaf(gx, gx, q1);
      s2 += gy; q2 = fmaf(gy, gy, q2);
    }
    *(float4*)(p1d + base) = make_float4(gxv[0],gxv[1],gxv[2],gxv[3]);
    *(float4*)(p2d + base) = make_float4(gyv[0],gyv[1],gyv[2],gyv[3]);
  }
#pragma unroll
  for (int off = 32; off >= 1; off >>= 1) {
    s0 += __shfl_xor(s0, off); q0 += __shfl_xor(q0, off);
    s1 += __shfl_xor(s1, off); q1 += __shfl_xor(q1, off);
    s2 += __shfl_xor(s2, off); q2 += __shfl_xor(q2, off);
  }
  int lane = t & 63, wv = t >> 6;
  if (lane == 0) {
    red[wv][0]=s0; red[wv][1]=q0; red[wv][2]=s1;
    red[wv][3]=q1; red[wv][4]=s2; red[wv][5]=q2;
  }
  __syncthreads();
  if (t == 0) {
    float r[6];
#pragma unroll
    for (int u = 0; u < 6; u++) r[u] = red[0][u]+red[1][u]+red[2][u]+red[3][u];
    size_t sb = (size_t)b*NFIN*2;
    stats[sb + (size_t)( c     )*2    ] = r[0];
    stats[sb + (size_t)( c     )*2 + 1] = r[1];
    stats[sb + (size_t)( 64+c  )*2    ] = r[2];
    stats[sb + (size_t)( 64+c  )*2 + 1] = r[3];
    stats[sb + (size_t)(128+c  )*2    ] = r[4];
    stats[sb + (size_t)(128+c  )*2 + 1] = r[5];
  }
}

// einsum + residual update. block = (pixel tile of 128, b); lane = o; 32 px/thread.
__global__ __launch_bounds__(256) void k_gemm(const float* __restrict__ st,
    float* __restrict__ stn, const float* __restrict__ p1, const float* __restrict__ p2,
    const float* __restrict__ stats, const float* __restrict__ wT,
    const float* __restrict__ bvec, const float* __restrict__ leakp) {
  int pt = blockIdx.x, b = blockIdx.y, t = threadIdx.x;
  __shared__ float w2[NFIN*NC];     // [c][o], scaled by s[c]
  __shared__ float mu_s[NFIN], sv_s[NFIN];
  __shared__ float bias2[NC];
  if (t < NFIN) {
    float s = stats[(size_t)b*NFIN*2 + t*2];
    float q = stats[(size_t)b*NFIN*2 + t*2 + 1];
    float mu = s * (1.f/HW);
    float var = fmaxf(q*(1.f/HW) - mu*mu, 0.f);
    mu_s[t] = mu;
    sv_s[t] = 1.f / sqrtf(var + 1e-5f);
  }
  __syncthreads();
  const float* wg = wT + (size_t)b*NFIN*NC;
#pragma unroll
  for (int i = 0; i < 48; i++) {
    int idx = i*256 + t;
    w2[idx] = wg[idx] * sv_s[idx >> 6];
  }
  __syncthreads();
  if (t < NC) {
    float bias = bvec[b*NC + t];
    for (int cc = 0; cc < NFIN; cc++) bias = fmaf(-w2[cc*64 + t], mu_s[cc], bias);
    bias2[t] = bias;
  }
  __syncthreads();

  int lane = t & 63;
  int wvi = __builtin_amdgcn_readfirstlane(t >> 6);
  int pixbase = pt*128 + wvi*32;
  const float* stb = st + (size_t)b*NC*HW;
  const float* p1b = p1 + (size_t)b*NC*HW;
  const float* p2b = p2 + (size_t)b*NC*HW;
  float leak = fminf(fmaxf(leakp[0], 0.001f), 1000.f);
  float acc[32];
#pragma unroll
  for (int j = 0; j < 32; j++) acc[j] = 0.f;

#define KSEG(BASEPTR, COFF)                                              \
  for (int c0 = 0; c0 < 64; c0++) {                                      \
    const float* sp = (BASEPTR) + (size_t)c0*HW + pixbase;               \
    sp = (const float*)__builtin_assume_aligned(sp, 128);                \
    float wvv = w2[(COFF + c0)*64 + lane];                               \
    _Pragma("unroll")                                                    \
    for (int j = 0; j < 32; j++) acc[j] = fmaf(wvv, sp[j], acc[j]);      \
  }
  KSEG(stb, 0)
  KSEG(p1b, 64)
  KSEG(p2b, 128)
#undef KSEG

  float bz = bias2[lane];
  size_t obase = (size_t)(b*NC + lane)*HW + pixbase;
#pragma unroll
  for (int j8 = 0; j8 < 8; j8++) {
    float4 ov = *(const float4*)(st + obase + j8*4);
    float4 nv;
    nv.x = ov.x + leak*(acc[j8*4+0] + bz);
    nv.y = ov.y + leak*(acc[j8*4+1] + bz);
    nv.z = ov.z + leak*(acc[j8*4+2] + bz);
    nv.w = ov.w + leak*(acc[j8*4+3] + bz);
    *(float4*)(stn + obase + j8*4) = nv;
  }
}

__global__ void k_final(const float* __restrict__ stF, float* __restrict__ out0,
                        float* __restrict__ out2) {
  int i4 = (blockIdx.x*256 + threadIdx.x)*4;
  int b = i4 / 12288, r = i4 % 12288;   // r = ch*4096 + pix, ch<3
  float4 v = *(const float4*)(stF + (size_t)b*(NC*HW) + r);
  float4 cv;
  cv.x = fminf(fmaxf(v.x,-1.f),1.f);
  cv.y = fminf(fmaxf(v.y,-1.f),1.f);
  cv.z = fminf(fmaxf(v.z,-1.f),1.f);
  cv.w = fminf(fmaxf(v.w,-1.f),1.f);
  *(float4*)(out0 + i4) = cv;
  *(float4*)(out2 + i4) = v;
}

extern "C" void kernel_launch(void* const* d_in, const int* in_sizes, int n_in,
                              void* d_out, int out_size, void* d_ws, size_t ws_size,
                              hipStream_t stream) {
  const float* lat   = (const float*)d_in[0];
  const float* Wk    = (const float*)d_in[1];
  const float* bk    = (const float*)d_in[2];
  const float* Wb    = (const float*)d_in[3];
  const float* bb    = (const float*)d_in[4];
  const float* leakp = (const float*)d_in[5];
  float* out = (float*)d_out;
  float* ws  = (float*)d_ws;
  float* wT    = ws + WS_WT;
  float* bvec  = ws + WS_BV;
  float* latT  = ws + WS_LATT;
  float* stats = ws + WS_STATS;
  float* p1    = ws + WS_P1;
  float* p2    = ws + WS_P2;
  float* out0 = out;                         // clipped final[:, :3]
  float* embs = out + 196608;                // 17 state slices
  float* out2 = out + 196608 + 17*SLICE;     // raw final[:, :3]

  hipLaunchKernelGGL(k_latT, dim3(1),    dim3(256), 0, stream, lat, latT);
  hipLaunchKernelGGL(k_w,    dim3(49),   dim3(256), 0, stream, latT, Wk, bk, Wb, bb, wT, bvec);
  hipLaunchKernelGGL(k_init, dim3(4096), dim3(256), 0, stream, embs);
  for (int tstep = 0; tstep < NSTEP; tstep++) {
    const float* stc = embs + (size_t)tstep*SLICE;
    float*       stn = embs + (size_t)(tstep+1)*SLICE;
    hipLaunchKernelGGL(k_cs,   dim3(64,16), dim3(256), 0, stream, stc, p1, p2, stats);
    hipLaunchKernelGGL(k_gemm, dim3(32,16), dim3(256), 0, stream, stc, stn, p1, p2, stats, wT, bvec, leakp);
  }
  hipLaunchKernelGGL(k_final, dim3(192), dim3(256), 0, stream,
                     embs + (size_t)NSTEP*SLICE, out0, out2);
}

// Round 3
// 730.240 us; speedup vs baseline: 1.8261x; 1.8261x over previous
//
#include <hip/hip_runtime.h>
#include <cstdint>
#include <cstddef>

#define NB 16
#define NC 64
#define HW 4096
#define SLICE ((size_t)(NB*NC*HW))   // 4194304 floats per state
#define NSTEP 16

// ws layout (float offsets)
#define WS_WT    ((size_t)0)          // wT  [16][3][64 o][64 c] = 196608
#define WS_BV    ((size_t)196608)     // bvec[16][64]            = 1024
#define WS_LATT  ((size_t)197632)     // latT[512][16]           = 8192
#define WS_SV    ((size_t)205824)     // sv  [16][3][64]         = 3072
#define WS_SVMU  ((size_t)208896)     // svmu[16][3][64]         = 3072

typedef _Float16 half8 __attribute__((ext_vector_type(8)));  // 8 f16 (4 VGPRs)
typedef float f32x4 __attribute__((ext_vector_type(4)));     // MFMA acc

__global__ void k_latT(const float* __restrict__ lat, float* __restrict__ latT) {
  int t = threadIdx.x;
  for (int idx = t; idx < 16*512; idx += 256) {
    int b = idx >> 9, k = idx & 511;
    latT[k*16 + b] = lat[idx];
  }
}

// wT[b][g][o][c] = (lat @ Wk + bk) at j = o*192 + (g*64+c) ; bvec = lat @ Wb + bb
__global__ __launch_bounds__(256) void k_w(const float* __restrict__ latT,
    const float* __restrict__ Wk, const float* __restrict__ bk,
    const float* __restrict__ Wb, const float* __restrict__ bb,
    float* __restrict__ wT, float* __restrict__ bvec) {
  int t = threadIdx.x;
  if (blockIdx.x < 48) {
    int j = blockIdx.x*256 + t;
    float acc[16];
#pragma unroll
    for (int b = 0; b < 16; b++) acc[b] = 0.f;
#pragma unroll 4
    for (int k = 0; k < 512; k++) {
      float wv = Wk[(size_t)k*12288 + j];
      const float* lt = (const float*)__builtin_assume_aligned(latT + k*16, 64);
#pragma unroll
      for (int b = 0; b < 16; b++) acc[b] = fmaf(lt[b], wv, acc[b]);
    }
    int o = j / 192, cf = j % 192;
    int g = cf >> 6, c = cf & 63;
    float bkj = bk[j];
#pragma unroll
    for (int b = 0; b < 16; b++)
      wT[(((size_t)(b*3 + g))*64 + o)*64 + c] = acc[b] + bkj;
  } else if (t < 64) {
    int j = t;
    float acc[16];
#pragma unroll
    for (int b = 0; b < 16; b++) acc[b] = 0.f;
    for (int k = 0; k < 512; k++) {
      float wv = Wb[k*64 + j];
      const float* lt = (const float*)__builtin_assume_aligned(latT + k*16, 64);
#pragma unroll
      for (int b = 0; b < 16; b++) acc[b] = fmaf(lt[b], wv, acc[b]);
    }
    float bbj = bb[j];
#pragma unroll
    for (int b = 0; b < 16; b++) bvec[b*64 + j] = acc[b] + bbj;
  }
}

__global__ void k_init(float* __restrict__ e0) {
  int idx4 = (blockIdx.x*256 + threadIdx.x) * 4;
  float4 v = make_float4(0.f, 0.f, 0.f, 0.f);
  if ((idx4 & 262143) == 2080) v.x = 1.0f;  // 32*64+32, channel 0
  *(float4*)(e0 + idx4) = v;
}

// per (b,c): moments of st, gx, gy (conv on the fly) -> sv, sv*mu for 3 groups
__global__ __launch_bounds__(256) void k_stats(const float* __restrict__ st,
    float* __restrict__ svb, float* __restrict__ svmub) {
  int c = blockIdx.x, b = blockIdx.y, t = threadIdx.x;
  __shared__ float img[HW];
  __shared__ float red[4][6];
  const size_t chan = (size_t)(b*NC + c) * HW;
  const float4* src4 = (const float4*)(st + chan);
  float4* img4 = (float4*)img;
#pragma unroll
  for (int i = 0; i < 4; i++) img4[i*256 + t] = src4[i*256 + t];
  __syncthreads();
  float s0=0,q0=0,s1=0,q1=0,s2=0,q2=0;
#pragma unroll
  for (int i = 0; i < 4; i++) {
    int base = i*1024 + t*4;
    int h = base >> 6, w0 = base & 63;
#pragma unroll
    for (int jj = 0; jj < 4; jj++) {
      int w = w0 + jj;
      bool wl = (w > 0), wr = (w < 63), hu = (h > 0), hd = (h < 63);
      float a00 = (hu && wl) ? img[(h-1)*64 + (w-1)] : 0.f;
      float a01 =  hu        ? img[(h-1)*64 +  w   ] : 0.f;
      float a02 = (hu && wr) ? img[(h-1)*64 + (w+1)] : 0.f;
      float a10 =  wl        ? img[ h   *64 + (w-1)] : 0.f;
      float a12 =  wr        ? img[ h   *64 + (w+1)] : 0.f;
      float a20 = (hd && wl) ? img[(h+1)*64 + (w-1)] : 0.f;
      float a21 =  hd        ? img[(h+1)*64 +  w   ] : 0.f;
      float a22 = (hd && wr) ? img[(h+1)*64 + (w+1)] : 0.f;
      float v = img[h*64 + w];
      float gx = (a02 - a00 + 2.f*(a12 - a10) + a22 - a20) * 0.125f;
      float gy = (a20 - a00 + 2.f*(a21 - a01) + a22 - a02) * 0.125f;
      s0 += v;  q0 = fmaf(v, v, q0);
      s1 += gx; q1 = fmaf(gx, gx, q1);
      s2 += gy; q2 = fmaf(gy, gy, q2);
    }
  }
#pragma unroll
  for (int off = 32; off >= 1; off >>= 1) {
    s0 += __shfl_xor(s0, off); q0 += __shfl_xor(q0, off);
    s1 += __shfl_xor(s1, off); q1 += __shfl_xor(q1, off);
    s2 += __shfl_xor(s2, off); q2 += __shfl_xor(q2, off);
  }
  int lane = t & 63, wv = t >> 6;
  if (lane == 0) {
    red[wv][0]=s0; red[wv][1]=q0; red[wv][2]=s1;
    red[wv][3]=q1; red[wv][4]=s2; red[wv][5]=q2;
  }
  __syncthreads();
  if (t == 0) {
    float r[6];
#pragma unroll
    for (int u = 0; u < 6; u++) r[u] = red[0][u]+red[1][u]+red[2][u]+red[3][u];
#pragma unroll
    for (int g = 0; g < 3; g++) {
      float mu  = r[2*g] * (1.f/HW);
      float var = fmaxf(r[2*g+1]*(1.f/HW) - mu*mu, 0.f);
      float sv  = 1.f / sqrtf(var + 1e-5f);
      svb  [b*192 + g*64 + c] = sv;
      svmub[b*192 + g*64 + c] = sv * mu;
    }
  }
}

// Fused: mix raw st with scaled W (MFMA f16 hi/lo), sobel AFTER mix (in-register),
// bias (bvec - sum w*sv*mu), residual update. Block = (image row r, batch b).
__global__ __launch_bounds__(256, 2) void k_fused(const float* __restrict__ st,
    float* __restrict__ stn, const float* __restrict__ wT,
    const float* __restrict__ bvec, const float* __restrict__ svb,
    const float* __restrict__ svmub, const float* __restrict__ leakp) {
  int r = blockIdx.x, b = blockIdx.y, t = threadIdx.x;
  __shared__ __align__(16) float rawL[32*200];        // [c_rel][3 rows*64 px], pad 200
  __shared__ __align__(16) _Float16 Bhi[4*192*8];     // [c8][px][cj]
  __shared__ __align__(16) _Float16 Blo[4*192*8];
  __shared__ __align__(16) _Float16 Whi[3*64*32];     // [g][o][c_rel], slot-swizzled
  __shared__ __align__(16) _Float16 Wlo[3*64*32];
  __shared__ float svL[192], svmuL[192], biasL[192], bvecL[64];

  if (t < 192) { svL[t] = svb[b*192 + t]; svmuL[t] = svmub[b*192 + t]; }
  if (t < 64) bvecL[t] = bvec[b*64 + t];
  float leak = fminf(fmaxf(leakp[0], 0.001f), 1000.f);

  int lane = t & 63;
  int wt = t >> 6;
  const float* stb = st + (size_t)b*NC*HW;
  float biasacc = 0.f;
  f32x4 accA[4] = {}; f32x4 accB[12] = {}; f32x4 accC[12] = {};

  for (int kc = 0; kc < 2; kc++) {
    __syncthreads();   // also covers svL/bvecL readiness on kc==0
    // ---- stage raw st window (3 rows x 32 channels), full rows ----
#pragma unroll
    for (int i = 0; i < 6; i++) {
      int u = t + i*256;             // [0,1536) float4 units
      int c_rel = u / 48, q = u % 48;
      int rho = q >> 4, quad = q & 15;
      int row = r - 1 + rho;
      float4 v = make_float4(0.f,0.f,0.f,0.f);
      if (row >= 0 && row < 64)
        v = *(const float4*)(stb + (size_t)(kc*32 + c_rel)*HW + row*64 + quad*4);
      *(float4*)(rawL + c_rel*200 + rho*64 + quad*4) = v;
    }
    // ---- stage scaled W (hi/lo f16) + bias dot ----
    if (t < 192) {
      int g = t >> 6, o = t & 63;
      const float* wrow = wT + (((size_t)(b*3 + g))*64 + o)*64 + kc*32;
#pragma unroll
      for (int s = 0; s < 4; s++) {
        float4 va = *(const float4*)(wrow + s*8);
        float4 vb = *(const float4*)(wrow + s*8 + 4);
        float wv[8] = {va.x,va.y,va.z,va.w,vb.x,vb.y,vb.z,vb.w};
        half8 hv, lv;
#pragma unroll
        for (int jj = 0; jj < 8; jj++) {
          int cg = g*64 + kc*32 + s*8 + jj;
          float scaled = wv[jj] * svL[cg];
          biasacc = fmaf(wv[jj], svmuL[cg], biasacc);
          _Float16 h = (_Float16)scaled;
          hv[jj] = h;
          lv[jj] = (_Float16)(scaled - (float)h);
        }
        int sidx = (g*64 + o)*32 + ((s ^ (o & 3)) << 3);
        *(half8*)(Whi + sidx) = hv;
        *(half8*)(Wlo + sidx) = lv;
      }
    }
    __syncthreads();
    // ---- transpose rawL -> cj-packed f16 hi/lo planes ----
#pragma unroll
    for (int i = 0; i < 3; i++) {
      int v = t + i*256;            // 768 units
      int c8 = v / 192, px = v % 192;
      half8 hv, lv;
#pragma unroll
      for (int ii = 0; ii < 8; ii++) {
        float x = rawL[(c8*8 + ii)*200 + px];
        _Float16 h = (_Float16)x;
        hv[ii] = h;
        lv[ii] = (_Float16)(x - (float)h);
      }
      *(half8*)(Bhi + (c8*192 + px)*8) = hv;
      *(half8*)(Blo + (c8*192 + px)*8) = lv;
    }
    __syncthreads();
    // ---- MFMA ----
    half8 ahi[3], alo[3];
#pragma unroll
    for (int g = 0; g < 3; g++) {
      int oa = wt*16 + (lane & 15);
      int sidx = (g*64 + oa)*32 + (((lane >> 4) ^ (oa & 3)) << 3);
      ahi[g] = *(const half8*)(Whi + sidx);
      alo[g] = *(const half8*)(Wlo + sidx);
    }
#pragma unroll
    for (int n = 0; n < 12; n++) {
      int bidx = ((lane >> 4)*192 + n*16 + (lane & 15))*8;
      half8 bh = *(const half8*)(Bhi + bidx);
      half8 bl = *(const half8*)(Blo + bidx);
      accB[n] = __builtin_amdgcn_mfma_f32_16x16x32_f16(ahi[1], bh, accB[n], 0,0,0);
      accB[n] = __builtin_amdgcn_mfma_f32_16x16x32_f16(ahi[1], bl, accB[n], 0,0,0);
      accB[n] = __builtin_amdgcn_mfma_f32_16x16x32_f16(alo[1], bh, accB[n], 0,0,0);
      accC[n] = __builtin_amdgcn_mfma_f32_16x16x32_f16(ahi[2], bh, accC[n], 0,0,0);
      accC[n] = __builtin_amdgcn_mfma_f32_16x16x32_f16(ahi[2], bl, accC[n], 0,0,0);
      accC[n] = __builtin_amdgcn_mfma_f32_16x16x32_f16(alo[2], bh, accC[n], 0,0,0);
      if (n >= 4 && n < 8) {
        accA[n-4] = __builtin_amdgcn_mfma_f32_16x16x32_f16(ahi[0], bh, accA[n-4], 0,0,0);
        accA[n-4] = __builtin_amdgcn_mfma_f32_16x16x32_f16(ahi[0], bl, accA[n-4], 0,0,0);
        accA[n-4] = __builtin_amdgcn_mfma_f32_16x16x32_f16(alo[0], bh, accA[n-4], 0,0,0);
      }
    }
  }

  if (t < 192) biasL[t] = biasacc;
  __syncthreads();

  // ---- epilogue: in-register sobel on mixed images + bias + residual ----
#pragma unroll
  for (int j = 0; j < 4; j++) {
    int o = wt*16 + ((lane >> 4) << 2) + j;
    float Sx[4], Sy[4];
#pragma unroll
    for (int nc = 0; nc < 4; nc++) {
      Sx[nc] = accB[nc][j] + 2.f*accB[4+nc][j] + accB[8+nc][j];
      Sy[nc] = accC[8+nc][j] - accC[nc][j];
    }
    float bt = bvecL[o] - biasL[o] - biasL[64+o] - biasL[128+o];
#pragma unroll
    for (int nc = 0; nc < 4; nc++) {
      int nm = (nc > 0) ? nc-1 : 0;
      int np = (nc < 3) ? nc+1 : 3;
      float xl1 = __shfl(Sx[nc], (lane - 1) & 63);
      float xl2 = (nc > 0) ? __shfl(Sx[nm], (lane + 15) & 63) : 0.f;
      float xL  = (lane & 15) ? xl1 : xl2;
      float xr1 = __shfl(Sx[nc], (lane + 1) & 63);
      float xr2 = (nc < 3) ? __shfl(Sx[np], (lane - 15) & 63) : 0.f;
      float xR  = ((lane & 15) == 15) ? xr2 : xr1;
      float yl1 = __shfl(Sy[nc], (lane - 1) & 63);
      float yl2 = (nc > 0) ? __shfl(Sy[nm], (lane + 15) & 63) : 0.f;
      float yL  = (lane & 15) ? yl1 : yl2;
      float yr1 = __shfl(Sy[nc], (lane + 1) & 63);
      float yr2 = (nc < 3) ? __shfl(Sy[np], (lane - 15) & 63) : 0.f;
      float yR  = ((lane & 15) == 15) ? yr2 : yr1;
      float gx = (xR - xL) * 0.125f;
      float gy = (yL + 2.f*Sy[nc] + yR) * 0.125f;
      float nw = accA[nc][j] + gx + gy + bt;
      int w = nc*16 + (lane & 15);
      size_t gi = (size_t)(b*NC + o)*HW + (size_t)r*64 + w;
      stn[gi] = st[gi] + leak * nw;
    }
  }
}

__global__ void k_final(const float* __restrict__ stF, float* __restrict__ out0,
                        float* __restrict__ out2) {
  int i4 = (blockIdx.x*256 + threadIdx.x)*4;
  int b = i4 / 12288, rr = i4 % 12288;
  float4 v = *(const float4*)(stF + (size_t)b*(NC*HW) + rr);
  float4 cv;
  cv.x = fminf(fmaxf(v.x,-1.f),1.f);
  cv.y = fminf(fmaxf(v.y,-1.f),1.f);
  cv.z = fminf(fmaxf(v.z,-1.f),1.f);
  cv.w = fminf(fmaxf(v.w,-1.f),1.f);
  *(float4*)(out0 + i4) = cv;
  *(float4*)(out2 + i4) = v;
}

extern "C" void kernel_launch(void* const* d_in, const int* in_sizes, int n_in,
                              void* d_out, int out_size, void* d_ws, size_t ws_size,
                              hipStream_t stream) {
  const float* lat   = (const float*)d_in[0];
  const float* Wk    = (const float*)d_in[1];
  const float* bk    = (const float*)d_in[2];
  const float* Wb    = (const float*)d_in[3];
  const float* bb    = (const float*)d_in[4];
  const float* leakp = (const float*)d_in[5];
  float* out = (float*)d_out;
  float* ws  = (float*)d_ws;
  float* wT    = ws + WS_WT;
  float* bvec  = ws + WS_BV;
  float* latT  = ws + WS_LATT;
  float* svbuf = ws + WS_SV;
  float* svmub = ws + WS_SVMU;
  float* out0 = out;
  float* embs = out + 196608;
  float* out2 = out + 196608 + 17*SLICE;

  hipLaunchKernelGGL(k_latT, dim3(1),    dim3(256), 0, stream, lat, latT);
  hipLaunchKernelGGL(k_w,    dim3(49),   dim3(256), 0, stream, latT, Wk, bk, Wb, bb, wT, bvec);
  hipLaunchKernelGGL(k_init, dim3(4096), dim3(256), 0, stream, embs);
  for (int tstep = 0; tstep < NSTEP; tstep++) {
    const float* stc = embs + (size_t)tstep*SLICE;
    float*       stn = embs + (size_t)(tstep+1)*SLICE;
    hipLaunchKernelGGL(k_stats, dim3(64,16), dim3(256), 0, stream, stc, svbuf, svmub);
    hipLaunchKernelGGL(k_fused, dim3(64,16), dim3(256), 0, stream,
                       stc, stn, wT, bvec, svbuf, svmub, leakp);
  }
  hipLaunchKernelGGL(k_final, dim3(192), dim3(256), 0, stream,
                     embs + (size_t)NSTEP*SLICE, out0, out2);
}